// Round 9
// baseline (595.786 us; speedup 1.0000x reference)
//
#include <hip/hip_runtime.h>
#include <hip/hip_bf16.h>
#include <math.h>

#define N_NODES 10000
#define E_RAW   320000
#define E_TOT   330000   // + self loops
#define DIM     256
#define HID     256
#define OUTD    64
#define LAYERS  4

typedef short    short8 __attribute__((ext_vector_type(8)));   // bf16x8 MFMA frag
typedef float    f32x4  __attribute__((ext_vector_type(4)));
typedef _Float16 h4v    __attribute__((ext_vector_type(4)));   // fp16x4

// ---- bf16 split helpers (manual RNE bit math) ----------------------------
__device__ __forceinline__ ushort f2bf(float f) {
    union { float f; unsigned u; } v; v.f = f;
    unsigned r = v.u + 0x7FFF + ((v.u >> 16) & 1);
    return (ushort)(r >> 16);
}
__device__ __forceinline__ float bf2f(ushort h) {
    union { unsigned u; float f; } v; v.u = ((unsigned)h) << 16;
    return v.f;
}
__device__ __forceinline__ void split_bf(float f, ushort& hi, ushort& lo) {
    hi = f2bf(f);
    lo = f2bf(f - bf2f(hi));
}

// ---- async global->LDS (width 16), fragment-ordered staging --------------
__device__ __forceinline__ void gload16(const void* g, void* l) {
    __builtin_amdgcn_global_load_lds(
        (const __attribute__((address_space(1))) unsigned int*)g,
        (__attribute__((address_space(3))) unsigned int*)l,
        16, 0, 0);
}

// ---------------------------------------------------------------------------
// CSR build (dst-sorted edge list)
// ---------------------------------------------------------------------------
__global__ void edge_hist(const int* __restrict__ ei, int* __restrict__ deg) {
    int e = blockIdx.x * blockDim.x + threadIdx.x;
    if (e >= E_TOT) return;
    int d = (e < E_RAW) ? ei[E_RAW + e] : (e - E_RAW);
    atomicAdd(&deg[d], 1);
}

__global__ __launch_bounds__(1024) void scan_deg(const int* __restrict__ deg,
                                                 int* __restrict__ row_start) {
    __shared__ int ps[1024];
    int t = threadIdx.x;
    int begin = t * 10;
    int end   = begin + 10; if (end > N_NODES) end = N_NODES;
    int s = 0;
    for (int i = begin; i < end; ++i) s += deg[i];
    ps[t] = s;
    __syncthreads();
    for (int off = 1; off < 1024; off <<= 1) {
        int v = (t >= off) ? ps[t - off] : 0;
        __syncthreads();
        ps[t] += v;
        __syncthreads();
    }
    int excl = (t == 0) ? 0 : ps[t - 1];
    for (int i = begin; i < end; ++i) {
        row_start[i] = excl;
        excl += deg[i];
    }
    if (t == 1023) row_start[N_NODES] = ps[1023];
}

__global__ void edge_scatter(const int* __restrict__ ei, const int* __restrict__ row_start,
                             int* __restrict__ cursor, int* __restrict__ ssrc) {
    int e = blockIdx.x * blockDim.x + threadIdx.x;
    if (e >= E_TOT) return;
    int s, d;
    if (e < E_RAW) { s = ei[e]; d = ei[E_RAW + e]; }
    else           { s = e - E_RAW; d = s; }
    int pos = row_start[d] + atomicAdd(&cursor[d], 1);
    ssrc[pos] = s;
}

// ---------------------------------------------------------------------------
// Split pre-passes (fp32 -> bf16 hi/lo), once per call
// ---------------------------------------------------------------------------
// LSTM folded + gate-interleaved weights, K=512:
//   original row R = gate*256 + hu  ->  stored row g' = (hu>>4)*64 + gate*16 + (hu&15)
//   value = wih[l][R][k]  (+ whh[l][R][k-256] for l>0, k>=256; layer0 h==0)
__global__ void split_lstm_w(const float* __restrict__ wih, const float* __restrict__ whh,
                             ushort* __restrict__ wh, ushort* __restrict__ wl) {
    int gid = blockIdx.x * blockDim.x + threadIdx.x;        // over 4*1024*512/4
    if (gid >= LAYERS * 1024 * 512 / 4) return;
    int i4  = gid * 4;
    int l   = i4 / (1024 * 512);
    int rem = i4 - l * (1024 * 512);
    int R   = rem / 512;
    int k   = rem - R * 512;
    float4 v = *reinterpret_cast<const float4*>(wih + ((size_t)(l * 1024 + R) * 512) + k);
    if (l > 0 && k >= 256) {
        float4 w2 = *reinterpret_cast<const float4*>(whh + ((size_t)(l * 1024 + R) * 256) + (k - 256));
        v.x += w2.x; v.y += w2.y; v.z += w2.z; v.w += w2.w;
    }
    int gate = R >> 8, hu = R & 255;
    int gp = ((hu >> 4) << 6) + (gate << 4) + (hu & 15);    // interleaved row
    ushort4 h4, l4;
    split_bf(v.x, h4.x, l4.x); split_bf(v.y, h4.y, l4.y);
    split_bf(v.z, h4.z, l4.z); split_bf(v.w, h4.w, l4.w);
    size_t dst = (size_t)(l * 1024 + gp) * 512 + k;
    *reinterpret_cast<ushort4*>(wh + dst) = h4;
    *reinterpret_cast<ushort4*>(wl + dst) = l4;
}

// gat: gwT[l*256+n][k] <- gat_w[l][k][n]   (transpose to [N][K])
__global__ void split_gat_w(const float* __restrict__ gat_w,
                            ushort* __restrict__ gh, ushort* __restrict__ gl) {
    int gid = blockIdx.x * blockDim.x + threadIdx.x;        // over 4*256*64
    if (gid >= LAYERS * 256 * 64) return;
    int l   = gid >> 14;
    int rem = gid & 16383;
    int n   = rem >> 6;
    int k4  = (rem & 63) * 4;
    ushort4 h4, l4;
    float v0 = gat_w[((size_t)l * 256 + k4 + 0) * 256 + n];
    float v1 = gat_w[((size_t)l * 256 + k4 + 1) * 256 + n];
    float v2 = gat_w[((size_t)l * 256 + k4 + 2) * 256 + n];
    float v3 = gat_w[((size_t)l * 256 + k4 + 3) * 256 + n];
    split_bf(v0, h4.x, l4.x); split_bf(v1, h4.y, l4.y);
    split_bf(v2, h4.z, l4.z); split_bf(v3, h4.w, l4.w);
    size_t dst = ((size_t)l * 256 + n) * 256 + k4;
    *reinterpret_cast<ushort4*>(gh + dst) = h4;
    *reinterpret_cast<ushort4*>(gl + dst) = l4;
}

// generic transpose-split: dst[n][k] <- w[k][n]   (w is [K][N] row-major)
__global__ void split_wT(const float* __restrict__ w, ushort* __restrict__ oh,
                         ushort* __restrict__ ol, int K, int N) {
    int gid = blockIdx.x * blockDim.x + threadIdx.x;   // over N*K
    if (gid >= N * K) return;
    int n = gid / K, k = gid - n * K;
    ushort hi, lo;
    split_bf(w[(size_t)k * N + n], hi, lo);
    oh[gid] = hi; ol[gid] = lo;
}

// contiguous split: fp32 -> bf16 pair
__global__ void split_x(const float* __restrict__ x, ushort* __restrict__ xh,
                        ushort* __restrict__ xl, int total4) {
    int gid = blockIdx.x * blockDim.x + threadIdx.x;   // over total/4
    if (gid >= total4) return;
    float4 v = *reinterpret_cast<const float4*>(x + (size_t)gid * 4);
    ushort4 h4, l4;
    split_bf(v.x, h4.x, l4.x); split_bf(v.y, h4.y, l4.y);
    split_bf(v.z, h4.z, l4.z); split_bf(v.w, h4.w, l4.w);
    *reinterpret_cast<ushort4*>(xh + (size_t)gid * 4) = h4;
    *reinterpret_cast<ushort4*>(xl + (size_t)gid * 4) = l4;
}

// ---------------------------------------------------------------------------
// Split-bf16 MFMA GEMM: C[M,N] = A[M,K] @ B[N,K]^T (+bias) via
// Ahi*Bhi + Ahi*Blo + Alo*Bhi. A: up to 2 virtual 256-wide k-segments
// (row stride 256 each). B row-major [N][K].
// BM=BN=128, 4 waves (2x2), wave tile 64x64, k-chunk 32.
// Staging: global_load_lds width-16, FRAGMENT-ORDERED LDS
//   (tile = 8 blks x [lane l: row=blk*16+(l&15), kgrp=(l>>4)*8] x 16B)
//   -> conflict-free b128 frag reads (lane-linear), no pad, no swizzle.
// Each wave stages one tile (Ah/Al/Bh/Bl). XCD-bijective block swizzle (m204).
// mode 0: fp32 C[row*N+col]
// mode 1: fp16 Xh[((col>>8)*M + row)*256 + (col&255)]   (layered GAT output)
// mode 2: bf16 pair Oh/Ol[row*N+col]
// mode 3: fused LSTM cell (N==1024, gate-interleaved B rows):
//         c[n*256+hu] rmw, h -> Oh/Ol[n*256+hu] bf16 pair
// ---------------------------------------------------------------------------
__global__ __launch_bounds__(256, 2) void gemm_bf3(
        const ushort* __restrict__ Ah0, const ushort* __restrict__ Al0,
        const ushort* __restrict__ Ah1, const ushort* __restrict__ Al1,
        const ushort* __restrict__ Bh,  const ushort* __restrict__ Bl,
        const float* __restrict__ bias,
        float* __restrict__ C, ushort* __restrict__ Oh, ushort* __restrict__ Ol,
        _Float16* __restrict__ Xh, float* __restrict__ Cc,
        int M, int N, int K, int mode) {
    __shared__ ushort lds[16384];   // 4 tiles x 8KB (8 blks x 64 lanes x 16B)

    int tid  = threadIdx.x;
    int lane = tid & 63;
    int w    = tid >> 6;
    int wm   = w >> 1, wn = w & 1;

    // XCD-bijective swizzle (m204): nwg need not be %8
    int gx = gridDim.x;
    int nwg = gx * gridDim.y;
    int orig = blockIdx.y * gx + blockIdx.x;
    int q8 = nwg >> 3, r7 = nwg & 7;
    int xcd = orig & 7, rest = orig >> 3;
    int wg = (xcd < r7 ? xcd * (q8 + 1) : r7 * (q8 + 1) + (xcd - r7) * q8) + rest;
    int bm = (wg % gx) * 128, bn = (wg / gx) * 128;

    f32x4 acc[4][4];
#pragma unroll
    for (int i = 0; i < 4; ++i)
#pragma unroll
        for (int j = 0; j < 4; ++j)
#pragma unroll
            for (int qq = 0; qq < 4; ++qq) acc[i][j][qq] = 0.f;

    int l15 = lane & 15;
    int skg = (lane >> 4) * 8;    // k-offset within 32-chunk (staging + frag)

    for (int k0 = 0; k0 < K; k0 += 32) {
        // --- stage: wave w stages tile w (8 x gload16) ---
        const ushort* gs;
        if (w == 0)      gs = (k0 < 256) ? Ah0 : Ah1;
        else if (w == 1) gs = (k0 < 256) ? Al0 : Al1;
        else if (w == 2) gs = Bh;
        else             gs = Bl;
        int    rowbase = (w < 2) ? bm : bn;
        size_t rstride = (w < 2) ? 256 : (size_t)K;
        int    kk      = (w < 2) ? ((k0 & 255) + skg) : (k0 + skg);
#pragma unroll
        for (int blk = 0; blk < 8; ++blk) {
            const ushort* g = gs + (size_t)(rowbase + blk * 16 + l15) * rstride + kk;
            int lidx = __builtin_amdgcn_readfirstlane(w * 4096 + blk * 512);
            gload16(g, (void*)&lds[lidx]);
        }
        __syncthreads();   // drains vmcnt -> all 4 tiles resident

        short8 afh[4], afl[4], bfh[4], bfl[4];
#pragma unroll
        for (int i = 0; i < 4; ++i) {
            afh[i] = *reinterpret_cast<const short8*>(&lds[        (wm * 4 + i) * 512 + lane * 8]);
            afl[i] = *reinterpret_cast<const short8*>(&lds[ 4096 + (wm * 4 + i) * 512 + lane * 8]);
            bfh[i] = *reinterpret_cast<const short8*>(&lds[ 8192 + (wn * 4 + i) * 512 + lane * 8]);
            bfl[i] = *reinterpret_cast<const short8*>(&lds[12288 + (wn * 4 + i) * 512 + lane * 8]);
        }
#pragma unroll
        for (int i = 0; i < 4; ++i)
#pragma unroll
            for (int j = 0; j < 4; ++j)
                acc[i][j] = __builtin_amdgcn_mfma_f32_16x16x32_bf16(afh[i], bfh[j], acc[i][j], 0, 0, 0);
#pragma unroll
        for (int i = 0; i < 4; ++i)
#pragma unroll
            for (int j = 0; j < 4; ++j)
                acc[i][j] = __builtin_amdgcn_mfma_f32_16x16x32_bf16(afh[i], bfl[j], acc[i][j], 0, 0, 0);
#pragma unroll
        for (int i = 0; i < 4; ++i)
#pragma unroll
            for (int j = 0; j < 4; ++j)
                acc[i][j] = __builtin_amdgcn_mfma_f32_16x16x32_bf16(afl[i], bfh[j], acc[i][j], 0, 0, 0);
        __syncthreads();   // all waves done reading before next-iter staging
    }

    // epilogue: C/D layout col=lane&15, row=(lane>>4)*4+reg  [m89-verified]
    if (mode == 3) {
        // fused LSTM cell: lane's 4 j-fragments are gates i,f,g,o of one hu
        int hu = (((bn + wn * 64) >> 6) << 4) + l15;
#pragma unroll
        for (int i = 0; i < 4; ++i) {
#pragma unroll
            for (int rr = 0; rr < 4; ++rr) {
                int n = bm + wm * 64 + i * 16 + (lane >> 4) * 4 + rr;
                if (n >= M) continue;
                float ig = acc[i][0][rr], fg = acc[i][1][rr];
                float gg = acc[i][2][rr], og = acc[i][3][rr];
                float si = 1.f / (1.f + expf(-ig));
                float sf = 1.f / (1.f + expf(-fg));
                float so = 1.f / (1.f + expf(-og));
                size_t o = (size_t)n * 256 + hu;
                float cn = sf * Cc[o] + si * tanhf(gg);
                float hn = so * tanhf(cn);
                Cc[o] = cn;
                ushort hi2, lo2; split_bf(hn, hi2, lo2);
                Oh[o] = hi2; Ol[o] = lo2;
            }
        }
        return;
    }
#pragma unroll
    for (int i = 0; i < 4; ++i) {
        int row0 = bm + wm * 64 + i * 16 + (lane >> 4) * 4;
#pragma unroll
        for (int j = 0; j < 4; ++j) {
            int col = bn + wn * 64 + j * 16 + l15;
            if (col >= N) continue;
            float bs = bias ? bias[col] : 0.f;
#pragma unroll
            for (int rr = 0; rr < 4; ++rr) {
                int row = row0 + rr;
                if (row >= M) continue;
                float o = acc[i][j][rr] + bs;
                if (mode == 0) {
                    C[(size_t)row * N + col] = o;
                } else if (mode == 1) {
                    Xh[((size_t)(col >> 8) * M + row) * 256 + (col & 255)] = (_Float16)o;
                } else {
                    ushort hi, lo; split_bf(o, hi, lo);
                    Oh[(size_t)row * N + col] = hi;
                    Ol[(size_t)row * N + col] = lo;
                }
            }
        }
    }
}

// ---------------------------------------------------------------------------
// Batched a_s/a_d from fp16 xw: one wave per (layer,node)   [R5-proven]
// ---------------------------------------------------------------------------
__global__ void compute_asd(const _Float16* __restrict__ xw_all,
                            const float* __restrict__ asrc_all,
                            const float* __restrict__ adst_all,
                            float* __restrict__ a_s, float* __restrict__ a_d) {
    int gt = blockIdx.x * blockDim.x + threadIdx.x;
    int gw = gt >> 6, lane = gt & 63;
    if (gw >= LAYERS * N_NODES) return;
    int l = gw / N_NODES;
    h4v v = *reinterpret_cast<const h4v*>(xw_all + (size_t)gw * 256 + lane * 4);
    float4 sa = *reinterpret_cast<const float4*>(asrc_all + l * 256 + lane * 4);
    float4 da = *reinterpret_cast<const float4*>(adst_all + l * 256 + lane * 4);
    float v0 = (float)v[0], v1 = (float)v[1], v2 = (float)v[2], v3 = (float)v[3];
    float s = v0*sa.x + v1*sa.y + v2*sa.z + v3*sa.w;
    float d = v0*da.x + v1*da.y + v2*da.z + v3*da.w;
    for (int off = 32; off; off >>= 1) {
        s += __shfl_down(s, off);
        d += __shfl_down(d, off);
    }
    if (lane == 0) { a_s[gw] = s; a_d[gw] = d; }
}

// ---------------------------------------------------------------------------
// Batched GAT softmax + aggregate (fp16 rows) + bias + tanh -> bf16 pair.
// *** R5 version verbatim (HW-proven @97.6us) — bisect control ***
// 256-thread blocks = 4 independent waves, one (layer,node) each.
// ---------------------------------------------------------------------------
__global__ __launch_bounds__(256) void gat_aggregate(const _Float16* __restrict__ xw_all,
                                                     const float* __restrict__ a_s,
                                                     const float* __restrict__ a_d,
                                                     const int* __restrict__ row_start,
                                                     const int* __restrict__ ssrc,
                                                     const float* __restrict__ gat_b,
                                                     ushort* __restrict__ htmph,
                                                     ushort* __restrict__ htmpl) {
    int gw = blockIdx.x * 4 + (threadIdx.x >> 6);   // (layer,node) index
    if (gw >= LAYERS * N_NODES) return;
    int l = gw / N_NODES, n = gw - l * N_NODES;
    int lane = threadIdx.x & 63;
    int beg = row_start[n], end = row_start[n + 1];
    const _Float16* xw = xw_all + (size_t)l * N_NODES * 256;
    const float* asl = a_s + (size_t)l * N_NODES;
    float adn = a_d[gw];

    // pass 1: max
    float lm = -3.4e38f;
    for (int e = beg + lane; e < end; e += 64) {
        float s = asl[ssrc[e]] + adn;
        s = (s > 0.f) ? s : 0.2f * s;
        lm = fmaxf(lm, s);
    }
    for (int off = 32; off; off >>= 1) lm = fmaxf(lm, __shfl_xor(lm, off));
    float m = lm;

    // pass 2: denom
    float ls = 0.f;
    for (int e = beg + lane; e < end; e += 64) {
        float s = asl[ssrc[e]] + adn;
        s = (s > 0.f) ? s : 0.2f * s;
        ls += expf(s - m);
    }
    for (int off = 32; off; off >>= 1) ls += __shfl_xor(ls, off);
    float inv = 1.f / ls;

    // pass 3: weighted gather; coef/src broadcast from owning lane via shfl
    float4 acc = make_float4(0.f, 0.f, 0.f, 0.f);
    for (int ch = beg; ch < end; ch += 64) {
        int e = ch + lane;
        float cfo = 0.f; int s0o = 0;
        if (e < end) {
            s0o = ssrc[e];
            float s = asl[s0o] + adn;
            s = (s > 0.f) ? s : 0.2f * s;
            cfo = expf(s - m) * inv;
        }
        int len = end - ch; if (len > 64) len = 64;
        for (int j = 0; j < len; ++j) {
            float cf = __shfl(cfo, j);
            int   s0 = __shfl(s0o, j);
            h4v v = *reinterpret_cast<const h4v*>(xw + (size_t)s0 * 256 + lane * 4);
            acc.x += cf * (float)v[0]; acc.y += cf * (float)v[1];
            acc.z += cf * (float)v[2]; acc.w += cf * (float)v[3];
        }
    }
    float4 b = *reinterpret_cast<const float4*>(gat_b + l * 256 + lane * 4);
    ushort4 h4, l4;
    split_bf(tanhf(acc.x + b.x), h4.x, l4.x);
    split_bf(tanhf(acc.y + b.y), h4.y, l4.y);
    split_bf(tanhf(acc.z + b.z), h4.z, l4.z);
    split_bf(tanhf(acc.w + b.w), h4.w, l4.w);
    size_t dst = (size_t)gw * 256 + lane * 4;
    *reinterpret_cast<ushort4*>(htmph + dst) = h4;
    *reinterpret_cast<ushort4*>(htmpl + dst) = l4;
}

// ---------------------------------------------------------------------------
extern "C" void kernel_launch(void* const* d_in, const int* in_sizes, int n_in,
                              void* d_out, int out_size, void* d_ws, size_t ws_size,
                              hipStream_t stream) {
    const float* x        = (const float*)d_in[0];
    const int*   ei       = (const int*)  d_in[1];
    const float* lin1_w   = (const float*)d_in[2];
    const float* lin1_b   = (const float*)d_in[3];
    const float* gat_w    = (const float*)d_in[4];   // [4,256,256]
    const float* gat_asrc = (const float*)d_in[5];   // [4,256]
    const float* gat_adst = (const float*)d_in[6];
    const float* gat_b    = (const float*)d_in[7];
    const float* lstm_wih = (const float*)d_in[8];   // [4,1024,512]
    const float* lstm_whh = (const float*)d_in[9];   // [4,1024,256]
    const float* lin2_w   = (const float*)d_in[10];  // [256,64]
    const float* lin2_b   = (const float*)d_in[11];
    float* out = (float*)d_out;

    size_t off = 0;
    auto alloc = [&](size_t bytes) -> void* {
        void* p = (char*)d_ws + off;
        off = (off + bytes + 255) & ~(size_t)255;
        return p;
    };
    ushort* xh     = (ushort*)alloc((size_t)N_NODES * DIM * 2);
    ushort* xl     = (ushort*)alloc((size_t)N_NODES * DIM * 2);
    ushort* x0h    = (ushort*)alloc((size_t)N_NODES * DIM * 2);
    ushort* x0l    = (ushort*)alloc((size_t)N_NODES * DIM * 2);
    _Float16* xwh  = (_Float16*)alloc((size_t)LAYERS * N_NODES * DIM * 2);
    ushort* htmph  = (ushort*)alloc((size_t)LAYERS * N_NODES * DIM * 2);
    ushort* htmpl  = (ushort*)alloc((size_t)LAYERS * N_NODES * DIM * 2);
    float*  c      = (float*) alloc((size_t)N_NODES * HID * 4);
    ushort* hbh[2], *hbl[2];
    hbh[0] = (ushort*)alloc((size_t)N_NODES * HID * 2);
    hbl[0] = (ushort*)alloc((size_t)N_NODES * HID * 2);
    hbh[1] = (ushort*)alloc((size_t)N_NODES * HID * 2);
    hbl[1] = (ushort*)alloc((size_t)N_NODES * HID * 2);
    float*  a_s    = (float*) alloc((size_t)LAYERS * N_NODES * 4);
    float*  a_d    = (float*) alloc((size_t)LAYERS * N_NODES * 4);
    int* row_start = (int*)   alloc((size_t)(N_NODES + 1) * 4);
    int* cursor    = (int*)   alloc((size_t)N_NODES * 4);
    int* ssrc      = (int*)   alloc((size_t)E_TOT * 4);
    ushort* wlh    = (ushort*)alloc((size_t)LAYERS * 1024 * 512 * 2);
    ushort* wll    = (ushort*)alloc((size_t)LAYERS * 1024 * 512 * 2);
    ushort* gwh    = (ushort*)alloc((size_t)LAYERS * 256 * 256 * 2);
    ushort* gwl    = (ushort*)alloc((size_t)LAYERS * 256 * 256 * 2);
    ushort* l1h    = (ushort*)alloc((size_t)256 * 256 * 2);
    ushort* l1l    = (ushort*)alloc((size_t)256 * 256 * 2);
    ushort* l2h    = (ushort*)alloc((size_t)128 * 256 * 2);   // padded to 128 rows
    ushort* l2l    = (ushort*)alloc((size_t)128 * 256 * 2);   // (B-tile overreads)
    (void)alloc(65536);   // tail guard for staging overreads

    // ---- CSR build ----
    hipMemsetAsync(cursor, 0, N_NODES * 4, stream);
    edge_hist<<<(E_TOT + 255) / 256, 256, 0, stream>>>(ei, cursor);
    scan_deg<<<1, 1024, 0, stream>>>(cursor, row_start);
    hipMemsetAsync(cursor, 0, N_NODES * 4, stream);
    edge_scatter<<<(E_TOT + 255) / 256, 256, 0, stream>>>(ei, row_start, cursor, ssrc);

    // ---- splits ----
    split_x<<<(N_NODES * DIM / 4 + 255) / 256, 256, 0, stream>>>(x, xh, xl, N_NODES * DIM / 4);
    split_lstm_w<<<(LAYERS * 1024 * 512 / 4 + 255) / 256, 256, 0, stream>>>(lstm_wih, lstm_whh, wlh, wll);
    split_gat_w<<<(LAYERS * 256 * 64 + 255) / 256, 256, 0, stream>>>(gat_w, gwh, gwl);
    split_wT<<<(256 * 256 + 255) / 256, 256, 0, stream>>>(lin1_w, l1h, l1l, 256, 256);
    split_wT<<<(64 * 256 + 255) / 256, 256, 0, stream>>>(lin2_w, l2h, l2l, 256, 64);

    // ---- init c ----
    hipMemsetAsync(c, 0, (size_t)N_NODES * HID * 4, stream);

    // ---- lin1: x0 = x @ lin1_w + b  (MFMA, bf16-pair out) ----
    {
        dim3 grid((N_NODES + 127) / 128, 256 / 128);
        gemm_bf3<<<grid, 256, 0, stream>>>(xh, xl, xh, xl,
                                           l1h, l1l, lin1_b,
                                           nullptr, x0h, x0l, nullptr, nullptr,
                                           N_NODES, 256, 256, 2);
    }

    // ---- batched GAT: projection (fp16 out), attention scalars, aggregate ----
    {
        dim3 grid((N_NODES + 127) / 128, (LAYERS * DIM) / 128);
        gemm_bf3<<<grid, 256, 0, stream>>>(x0h, x0l, x0h, x0l,
                                           gwh, gwl, nullptr,
                                           nullptr, nullptr, nullptr, xwh, nullptr,
                                           N_NODES, LAYERS * DIM, 256, 1);
        int waves = LAYERS * N_NODES;
        compute_asd<<<(waves * 64 + 255) / 256, 256, 0, stream>>>(xwh, gat_asrc, gat_adst,
                                                                  a_s, a_d);
        gat_aggregate<<<(waves + 3) / 4, 256, 0, stream>>>(xwh, a_s, a_d, row_start, ssrc,
                                                           gat_b, htmph, htmpl);
    }

    // ---- LSTM chain (K=512 folded weights, fused cell epilogue) ----
    for (int l = 0; l < LAYERS; ++l) {
        const ushort* xch = (l == 0) ? x0h : hbh[(l - 1) & 1];
        const ushort* xcl = (l == 0) ? x0l : hbl[(l - 1) & 1];
        dim3 gridL((N_NODES + 127) / 128, 1024 / 128);
        gemm_bf3<<<gridL, 256, 0, stream>>>(
            htmph + (size_t)l * N_NODES * DIM, htmpl + (size_t)l * N_NODES * DIM,
            xch, xcl,
            wlh + (size_t)l * 1024 * 512, wll + (size_t)l * 1024 * 512,
            nullptr, nullptr, hbh[l & 1], hbl[l & 1], nullptr, c,
            N_NODES, 1024, 512, 3);
    }

    // ---- lin2: out = h @ lin2_w + b  (MFMA, fp32 out) ----
    {
        dim3 grid((N_NODES + 127) / 128, 1);
        gemm_bf3<<<grid, 256, 0, stream>>>(hbh[1], hbl[1], hbh[1], hbl[1],
                                           l2h, l2l, lin2_b,
                                           out, nullptr, nullptr, nullptr, nullptr,
                                           N_NODES, OUTD, 256, 0);
    }
}

// Round 10
// 529.805 us; speedup vs baseline: 1.1245x; 1.1245x over previous
//
#include <hip/hip_runtime.h>
#include <hip/hip_bf16.h>
#include <math.h>

#define N_NODES 10000
#define N_PAD   10112    // ceil(10000/128)*128 — blocked-A padding
#define E_RAW   320000
#define E_TOT   330000   // + self loops
#define DIM     256
#define HID     256
#define OUTD    64
#define LAYERS  4

typedef short    short8 __attribute__((ext_vector_type(8)));   // bf16x8 MFMA frag
typedef float    f32x4  __attribute__((ext_vector_type(4)));
typedef _Float16 h4v    __attribute__((ext_vector_type(4)));   // fp16x4

// ---- blocked-fragment global layout -------------------------------------
// X[row][col] stored at ((row/16)*KC + col/32)*512 + ((col>>3)&3)*128 + (row&15)*8 + (col&7)
// so that one 16x32 block = 64 lanes x 16B contiguous, lane l = ((col>>3)&3)*16 + (row&15).
__host__ __device__ __forceinline__ size_t blk_off(int row, int col, int KC) {
    return (((size_t)(row >> 4) * KC + (col >> 5)) * 64
            + ((col >> 3) & 3) * 16 + (row & 15)) * 8 + (col & 7);
}

// ---- bf16 split helpers (manual RNE bit math) ----------------------------
__device__ __forceinline__ ushort f2bf(float f) {
    union { float f; unsigned u; } v; v.f = f;
    unsigned r = v.u + 0x7FFF + ((v.u >> 16) & 1);
    return (ushort)(r >> 16);
}
__device__ __forceinline__ float bf2f(ushort h) {
    union { unsigned u; float f; } v; v.u = ((unsigned)h) << 16;
    return v.f;
}
__device__ __forceinline__ void split_bf(float f, ushort& hi, ushort& lo) {
    hi = f2bf(f);
    lo = f2bf(f - bf2f(hi));
}

// ---- async global->LDS (width 16) ---------------------------------------
__device__ __forceinline__ void gload16(const void* g, void* l) {
    __builtin_amdgcn_global_load_lds(
        (const __attribute__((address_space(1))) unsigned int*)g,
        (__attribute__((address_space(3))) unsigned int*)l,
        16, 0, 0);
}

// ---------------------------------------------------------------------------
// CSR build (dst-sorted edge list)
// ---------------------------------------------------------------------------
__global__ void edge_hist(const int* __restrict__ ei, int* __restrict__ deg) {
    int e = blockIdx.x * blockDim.x + threadIdx.x;
    if (e >= E_TOT) return;
    int d = (e < E_RAW) ? ei[E_RAW + e] : (e - E_RAW);
    atomicAdd(&deg[d], 1);
}

__global__ __launch_bounds__(1024) void scan_deg(const int* __restrict__ deg,
                                                 int* __restrict__ row_start) {
    __shared__ int ps[1024];
    int t = threadIdx.x;
    int begin = t * 10;
    int end   = begin + 10; if (end > N_NODES) end = N_NODES;
    int s = 0;
    for (int i = begin; i < end; ++i) s += deg[i];
    ps[t] = s;
    __syncthreads();
    for (int off = 1; off < 1024; off <<= 1) {
        int v = (t >= off) ? ps[t - off] : 0;
        __syncthreads();
        ps[t] += v;
        __syncthreads();
    }
    int excl = (t == 0) ? 0 : ps[t - 1];
    for (int i = begin; i < end; ++i) {
        row_start[i] = excl;
        excl += deg[i];
    }
    if (t == 1023) row_start[N_NODES] = ps[1023];
}

__global__ void edge_scatter(const int* __restrict__ ei, const int* __restrict__ row_start,
                             int* __restrict__ cursor, int* __restrict__ ssrc) {
    int e = blockIdx.x * blockDim.x + threadIdx.x;
    if (e >= E_TOT) return;
    int s, d;
    if (e < E_RAW) { s = ei[e]; d = ei[E_RAW + e]; }
    else           { s = e - E_RAW; d = s; }
    int pos = row_start[d] + atomicAdd(&cursor[d], 1);
    ssrc[pos] = s;
}

// ---------------------------------------------------------------------------
// Split pre-passes (fp32 -> bf16 hi/lo), blocked-layout outputs
// ---------------------------------------------------------------------------
// LSTM folded + gate-interleaved weights, K=512, blocked KC=16:
__global__ void split_lstm_w(const float* __restrict__ wih, const float* __restrict__ whh,
                             ushort* __restrict__ wh, ushort* __restrict__ wl) {
    int gid = blockIdx.x * blockDim.x + threadIdx.x;        // over 4*1024*512/4
    if (gid >= LAYERS * 1024 * 512 / 4) return;
    int i4  = gid * 4;
    int l   = i4 / (1024 * 512);
    int rem = i4 - l * (1024 * 512);
    int R   = rem / 512;
    int k   = rem - R * 512;
    float4 v = *reinterpret_cast<const float4*>(wih + ((size_t)(l * 1024 + R) * 512) + k);
    if (l > 0 && k >= 256) {
        float4 w2 = *reinterpret_cast<const float4*>(whh + ((size_t)(l * 1024 + R) * 256) + (k - 256));
        v.x += w2.x; v.y += w2.y; v.z += w2.z; v.w += w2.w;
    }
    int gate = R >> 8, hu = R & 255;
    int gp = ((hu >> 4) << 6) + (gate << 4) + (hu & 15);    // interleaved row
    ushort4 h4, l4;
    split_bf(v.x, h4.x, l4.x); split_bf(v.y, h4.y, l4.y);
    split_bf(v.z, h4.z, l4.z); split_bf(v.w, h4.w, l4.w);
    size_t dst = (size_t)l * (1024 * 512) + blk_off(gp, k, 16);
    *reinterpret_cast<ushort4*>(wh + dst) = h4;
    *reinterpret_cast<ushort4*>(wl + dst) = l4;
}

// gat: blocked gwT[l][n][k] <- gat_w[l][k][n], KC=8
__global__ void split_gat_w(const float* __restrict__ gat_w,
                            ushort* __restrict__ gh, ushort* __restrict__ gl) {
    int gid = blockIdx.x * blockDim.x + threadIdx.x;        // over 4*256*64
    if (gid >= LAYERS * 256 * 64) return;
    int l   = gid >> 14;
    int rem = gid & 16383;
    int n   = rem >> 6;
    int k4  = (rem & 63) * 4;
    ushort4 h4, l4;
    float v0 = gat_w[((size_t)l * 256 + k4 + 0) * 256 + n];
    float v1 = gat_w[((size_t)l * 256 + k4 + 1) * 256 + n];
    float v2 = gat_w[((size_t)l * 256 + k4 + 2) * 256 + n];
    float v3 = gat_w[((size_t)l * 256 + k4 + 3) * 256 + n];
    split_bf(v0, h4.x, l4.x); split_bf(v1, h4.y, l4.y);
    split_bf(v2, h4.z, l4.z); split_bf(v3, h4.w, l4.w);
    size_t dst = (size_t)l * (256 * 256) + blk_off(n, k4, 8);
    *reinterpret_cast<ushort4*>(gh + dst) = h4;
    *reinterpret_cast<ushort4*>(gl + dst) = l4;
}

// generic transpose-split, blocked KC=8: dst[n][k] <- w[k][n]
__global__ void split_wT(const float* __restrict__ w, ushort* __restrict__ oh,
                         ushort* __restrict__ ol, int K, int N) {
    int gid = blockIdx.x * blockDim.x + threadIdx.x;   // over N*K
    if (gid >= N * K) return;
    int n = gid / K, k = gid - n * K;
    ushort hi, lo;
    split_bf(w[(size_t)k * N + n], hi, lo);
    size_t dst = blk_off(n, k, 8);
    oh[dst] = hi; ol[dst] = lo;
}

// contiguous split x[10000][256] -> blocked bf16 pair, KC=8
__global__ void split_x(const float* __restrict__ x, ushort* __restrict__ xh,
                        ushort* __restrict__ xl, int total4) {
    int gid = blockIdx.x * blockDim.x + threadIdx.x;   // over rows*64
    if (gid >= total4) return;
    int row = gid >> 6, c4 = (gid & 63) * 4;
    float4 v = *reinterpret_cast<const float4*>(x + (size_t)row * 256 + c4);
    ushort4 h4, l4;
    split_bf(v.x, h4.x, l4.x); split_bf(v.y, h4.y, l4.y);
    split_bf(v.z, h4.z, l4.z); split_bf(v.w, h4.w, l4.w);
    size_t dst = blk_off(row, c4, 8);
    *reinterpret_cast<ushort4*>(xh + dst) = h4;
    *reinterpret_cast<ushort4*>(xl + dst) = l4;
}

// ---------------------------------------------------------------------------
// Split-bf16 MFMA GEMM: C[M,N] = A[M,K] @ B[N,K]^T (+bias) via
// Ahi*Bhi + Ahi*Blo + Alo*Bhi. A,B in BLOCKED global layout (see blk_off):
// staging = 8 x gload16/wave, lane-contiguous 1KB bursts, linear LDS,
// conflict-free b128 fragment reads. A: up to 2 virtual 256-wide k-segments
// (KC=8 each). B: KC=K/32.
// BM=BN=128, 4 waves (2x2), wave tile 64x64, k-chunk 32. No XCD swizzle.
// mode 0: fp32 C[row*N+col]
// mode 1: fp16 Xh[((col>>8)*M + row)*256 + (col&255)]   (row-major GAT out)
// mode 2: bf16 pair Oh/Ol blocked KC=8 (GEMM-A-ready)
// mode 3: fused LSTM cell (N==1024, gate-interleaved B rows):
//         c[n*256+hu] rmw (linear), h -> Oh/Ol blocked KC=8
// ---------------------------------------------------------------------------
__global__ __launch_bounds__(256, 2) void gemm_bf3(
        const ushort* __restrict__ Ah0, const ushort* __restrict__ Al0,
        const ushort* __restrict__ Ah1, const ushort* __restrict__ Al1,
        const ushort* __restrict__ Bh,  const ushort* __restrict__ Bl,
        const float* __restrict__ bias,
        float* __restrict__ C, ushort* __restrict__ Oh, ushort* __restrict__ Ol,
        _Float16* __restrict__ Xh, float* __restrict__ Cc,
        int M, int N, int K, int mode) {
    __shared__ ushort lds[16384];   // 4 tiles x 8KB (8 blks x 64 lanes x 16B)

    int tid  = threadIdx.x;
    int lane = tid & 63;
    int w    = tid >> 6;
    int wm   = w >> 1, wn = w & 1;
    int bm = blockIdx.x * 128, bn = blockIdx.y * 128;

    f32x4 acc[4][4];
#pragma unroll
    for (int i = 0; i < 4; ++i)
#pragma unroll
        for (int j = 0; j < 4; ++j)
#pragma unroll
            for (int qq = 0; qq < 4; ++qq) acc[i][j][qq] = 0.f;

    int l15 = lane & 15;
    int KCb = K >> 5;   // B-operand blocked KC

    for (int k0 = 0; k0 < K; k0 += 32) {
        // --- stage: wave w stages tile w; lane reads its own contiguous 16B ---
        const ushort* gs;
        size_t boff;
        if (w < 2) {
            gs = (k0 < 256) ? (w == 0 ? Ah0 : Al0) : (w == 0 ? Ah1 : Al1);
            boff = (((size_t)(bm >> 4) * 8 + ((k0 & 255) >> 5)) * 64 + lane) * 8;
        } else {
            gs = (w == 2) ? Bh : Bl;
            boff = (((size_t)(bn >> 4) * KCb + (k0 >> 5)) * 64 + lane) * 8;
        }
        size_t bstride = (w < 2) ? (8 * 512) : ((size_t)KCb * 512);  // per 16-row block
#pragma unroll
        for (int blk = 0; blk < 8; ++blk) {
            const ushort* g = gs + boff + (size_t)blk * bstride;
            int lidx = __builtin_amdgcn_readfirstlane(w * 4096 + blk * 512);
            gload16(g, (void*)&lds[lidx]);
        }
        __syncthreads();   // drains vmcnt -> all 4 tiles resident

        short8 afh[4], afl[4], bfh[4], bfl[4];
#pragma unroll
        for (int i = 0; i < 4; ++i) {
            afh[i] = *reinterpret_cast<const short8*>(&lds[        (wm * 4 + i) * 512 + lane * 8]);
            afl[i] = *reinterpret_cast<const short8*>(&lds[ 4096 + (wm * 4 + i) * 512 + lane * 8]);
            bfh[i] = *reinterpret_cast<const short8*>(&lds[ 8192 + (wn * 4 + i) * 512 + lane * 8]);
            bfl[i] = *reinterpret_cast<const short8*>(&lds[12288 + (wn * 4 + i) * 512 + lane * 8]);
        }
#pragma unroll
        for (int i = 0; i < 4; ++i)
#pragma unroll
            for (int j = 0; j < 4; ++j)
                acc[i][j] = __builtin_amdgcn_mfma_f32_16x16x32_bf16(afh[i], bfh[j], acc[i][j], 0, 0, 0);
#pragma unroll
        for (int i = 0; i < 4; ++i)
#pragma unroll
            for (int j = 0; j < 4; ++j)
                acc[i][j] = __builtin_amdgcn_mfma_f32_16x16x32_bf16(afh[i], bfl[j], acc[i][j], 0, 0, 0);
#pragma unroll
        for (int i = 0; i < 4; ++i)
#pragma unroll
            for (int j = 0; j < 4; ++j)
                acc[i][j] = __builtin_amdgcn_mfma_f32_16x16x32_bf16(afl[i], bfh[j], acc[i][j], 0, 0, 0);
        __syncthreads();   // all waves done reading before next-iter staging
    }

    // epilogue: C/D layout col=lane&15, row=(lane>>4)*4+reg  [m89-verified]
    if (mode == 3) {
        // fused LSTM cell: lane's 4 j-fragments are gates i,f,g,o of one hu
        int hu = (((bn + wn * 64) >> 6) << 4) + l15;
#pragma unroll
        for (int i = 0; i < 4; ++i) {
#pragma unroll
            for (int rr = 0; rr < 4; ++rr) {
                int n = bm + wm * 64 + i * 16 + (lane >> 4) * 4 + rr;
                if (n >= M) continue;
                float ig = acc[i][0][rr], fg = acc[i][1][rr];
                float gg = acc[i][2][rr], og = acc[i][3][rr];
                float si = 1.f / (1.f + expf(-ig));
                float sf = 1.f / (1.f + expf(-fg));
                float so = 1.f / (1.f + expf(-og));
                size_t o = (size_t)n * 256 + hu;
                float cn = sf * Cc[o] + si * tanhf(gg);
                float hn = so * tanhf(cn);
                Cc[o] = cn;
                ushort hi2, lo2; split_bf(hn, hi2, lo2);
                size_t ob = blk_off(n, hu, 8);
                Oh[ob] = hi2; Ol[ob] = lo2;
            }
        }
        return;
    }
#pragma unroll
    for (int i = 0; i < 4; ++i) {
        int row0 = bm + wm * 64 + i * 16 + (lane >> 4) * 4;
#pragma unroll
        for (int j = 0; j < 4; ++j) {
            int col = bn + wn * 64 + j * 16 + l15;
            if (col >= N) continue;
            float bs = bias ? bias[col] : 0.f;
#pragma unroll
            for (int rr = 0; rr < 4; ++rr) {
                int row = row0 + rr;
                if (row >= M) continue;
                float o = acc[i][j][rr] + bs;
                if (mode == 0) {
                    C[(size_t)row * N + col] = o;
                } else if (mode == 1) {
                    Xh[((size_t)(col >> 8) * M + row) * 256 + (col & 255)] = (_Float16)o;
                } else {
                    ushort hi, lo; split_bf(o, hi, lo);
                    size_t ob = blk_off(row, col, 8);
                    Oh[ob] = hi;
                    Ol[ob] = lo;
                }
            }
        }
    }
}

// ---------------------------------------------------------------------------
// Batched a_s/a_d from fp16 xw (row-major): one wave per (layer,node)
// ---------------------------------------------------------------------------
__global__ void compute_asd(const _Float16* __restrict__ xw_all,
                            const float* __restrict__ asrc_all,
                            const float* __restrict__ adst_all,
                            float* __restrict__ a_s, float* __restrict__ a_d) {
    int gt = blockIdx.x * blockDim.x + threadIdx.x;
    int gw = gt >> 6, lane = gt & 63;
    if (gw >= LAYERS * N_NODES) return;
    int l = gw / N_NODES;
    h4v v = *reinterpret_cast<const h4v*>(xw_all + (size_t)gw * 256 + lane * 4);
    float4 sa = *reinterpret_cast<const float4*>(asrc_all + l * 256 + lane * 4);
    float4 da = *reinterpret_cast<const float4*>(adst_all + l * 256 + lane * 4);
    float v0 = (float)v[0], v1 = (float)v[1], v2 = (float)v[2], v3 = (float)v[3];
    float s = v0*sa.x + v1*sa.y + v2*sa.z + v3*sa.w;
    float d = v0*da.x + v1*da.y + v2*da.z + v3*da.w;
    for (int off = 32; off; off >>= 1) {
        s += __shfl_down(s, off);
        d += __shfl_down(d, off);
    }
    if (lane == 0) { a_s[gw] = s; a_d[gw] = d; }
}

// ---------------------------------------------------------------------------
// Batched GAT softmax + aggregate (fp16 rows) + bias + tanh.
// R5-proven structure; output now written in BLOCKED bf16-pair layout.
// ---------------------------------------------------------------------------
__global__ __launch_bounds__(256) void gat_aggregate(const _Float16* __restrict__ xw_all,
                                                     const float* __restrict__ a_s,
                                                     const float* __restrict__ a_d,
                                                     const int* __restrict__ row_start,
                                                     const int* __restrict__ ssrc,
                                                     const float* __restrict__ gat_b,
                                                     ushort* __restrict__ htmph,
                                                     ushort* __restrict__ htmpl) {
    int gw = blockIdx.x * 4 + (threadIdx.x >> 6);   // (layer,node) index
    if (gw >= LAYERS * N_NODES) return;
    int l = gw / N_NODES, n = gw - l * N_NODES;
    int lane = threadIdx.x & 63;
    int beg = row_start[n], end = row_start[n + 1];
    const _Float16* xw = xw_all + (size_t)l * N_NODES * 256;
    const float* asl = a_s + (size_t)l * N_NODES;
    float adn = a_d[gw];

    // pass 1: max
    float lm = -3.4e38f;
    for (int e = beg + lane; e < end; e += 64) {
        float s = asl[ssrc[e]] + adn;
        s = (s > 0.f) ? s : 0.2f * s;
        lm = fmaxf(lm, s);
    }
    for (int off = 32; off; off >>= 1) lm = fmaxf(lm, __shfl_xor(lm, off));
    float m = lm;

    // pass 2: denom
    float ls = 0.f;
    for (int e = beg + lane; e < end; e += 64) {
        float s = asl[ssrc[e]] + adn;
        s = (s > 0.f) ? s : 0.2f * s;
        ls += expf(s - m);
    }
    for (int off = 32; off; off >>= 1) ls += __shfl_xor(ls, off);
    float inv = 1.f / ls;

    // pass 3: weighted gather; coef/src broadcast from owning lane via shfl
    float4 acc = make_float4(0.f, 0.f, 0.f, 0.f);
    for (int ch = beg; ch < end; ch += 64) {
        int e = ch + lane;
        float cfo = 0.f; int s0o = 0;
        if (e < end) {
            s0o = ssrc[e];
            float s = asl[s0o] + adn;
            s = (s > 0.f) ? s : 0.2f * s;
            cfo = expf(s - m) * inv;
        }
        int len = end - ch; if (len > 64) len = 64;
        for (int j = 0; j < len; ++j) {
            float cf = __shfl(cfo, j);
            int   s0 = __shfl(s0o, j);
            h4v v = *reinterpret_cast<const h4v*>(xw + (size_t)s0 * 256 + lane * 4);
            acc.x += cf * (float)v[0]; acc.y += cf * (float)v[1];
            acc.z += cf * (float)v[2]; acc.w += cf * (float)v[3];
        }
    }
    float4 b = *reinterpret_cast<const float4*>(gat_b + l * 256 + lane * 4);
    ushort4 h4, l4;
    split_bf(tanhf(acc.x + b.x), h4.x, l4.x);
    split_bf(tanhf(acc.y + b.y), h4.y, l4.y);
    split_bf(tanhf(acc.z + b.z), h4.z, l4.z);
    split_bf(tanhf(acc.w + b.w), h4.w, l4.w);
    size_t dst = (size_t)l * ((size_t)N_PAD * 256) + blk_off(n, lane * 4, 8);
    *reinterpret_cast<ushort4*>(htmph + dst) = h4;
    *reinterpret_cast<ushort4*>(htmpl + dst) = l4;
}

// ---------------------------------------------------------------------------
extern "C" void kernel_launch(void* const* d_in, const int* in_sizes, int n_in,
                              void* d_out, int out_size, void* d_ws, size_t ws_size,
                              hipStream_t stream) {
    const float* x        = (const float*)d_in[0];
    const int*   ei       = (const int*)  d_in[1];
    const float* lin1_w   = (const float*)d_in[2];
    const float* lin1_b   = (const float*)d_in[3];
    const float* gat_w    = (const float*)d_in[4];   // [4,256,256]
    const float* gat_asrc = (const float*)d_in[5];   // [4,256]
    const float* gat_adst = (const float*)d_in[6];
    const float* gat_b    = (const float*)d_in[7];
    const float* lstm_wih = (const float*)d_in[8];   // [4,1024,512]
    const float* lstm_whh = (const float*)d_in[9];   // [4,1024,256]
    const float* lin2_w   = (const float*)d_in[10];  // [256,64]
    const float* lin2_b   = (const float*)d_in[11];
    float* out = (float*)d_out;

    size_t off = 0;
    auto alloc = [&](size_t bytes) -> void* {
        void* p = (char*)d_ws + off;
        off = (off + bytes + 255) & ~(size_t)255;
        return p;
    };
    ushort* xh     = (ushort*)alloc((size_t)N_PAD * DIM * 2);
    ushort* xl     = (ushort*)alloc((size_t)N_PAD * DIM * 2);
    ushort* x0h    = (ushort*)alloc((size_t)N_PAD * DIM * 2);
    ushort* x0l    = (ushort*)alloc((size_t)N_PAD * DIM * 2);
    _Float16* xwh  = (_Float16*)alloc((size_t)LAYERS * N_NODES * DIM * 2);
    ushort* htmph  = (ushort*)alloc((size_t)LAYERS * N_PAD * DIM * 2);
    ushort* htmpl  = (ushort*)alloc((size_t)LAYERS * N_PAD * DIM * 2);
    float*  c      = (float*) alloc((size_t)N_NODES * HID * 4);
    ushort* hbh[2], *hbl[2];
    hbh[0] = (ushort*)alloc((size_t)N_PAD * HID * 2);
    hbl[0] = (ushort*)alloc((size_t)N_PAD * HID * 2);
    hbh[1] = (ushort*)alloc((size_t)N_PAD * HID * 2);
    hbl[1] = (ushort*)alloc((size_t)N_PAD * HID * 2);
    float*  a_s    = (float*) alloc((size_t)LAYERS * N_NODES * 4);
    float*  a_d    = (float*) alloc((size_t)LAYERS * N_NODES * 4);
    int* row_start = (int*)   alloc((size_t)(N_NODES + 1) * 4);
    int* cursor    = (int*)   alloc((size_t)N_NODES * 4);
    int* ssrc      = (int*)   alloc((size_t)E_TOT * 4);
    ushort* wlh    = (ushort*)alloc((size_t)LAYERS * 1024 * 512 * 2);
    ushort* wll    = (ushort*)alloc((size_t)LAYERS * 1024 * 512 * 2);
    ushort* gwh    = (ushort*)alloc((size_t)LAYERS * 256 * 256 * 2);
    ushort* gwl    = (ushort*)alloc((size_t)LAYERS * 256 * 256 * 2);
    ushort* l1h    = (ushort*)alloc((size_t)256 * 256 * 2);
    ushort* l1l    = (ushort*)alloc((size_t)256 * 256 * 2);
    ushort* l2h    = (ushort*)alloc((size_t)128 * 256 * 2);   // padded to 128 rows
    ushort* l2l    = (ushort*)alloc((size_t)128 * 256 * 2);
    (void)alloc(65536);   // tail guard (belt-and-suspenders)

    // ---- CSR build ----
    hipMemsetAsync(cursor, 0, N_NODES * 4, stream);
    edge_hist<<<(E_TOT + 255) / 256, 256, 0, stream>>>(ei, cursor);
    scan_deg<<<1, 1024, 0, stream>>>(cursor, row_start);
    hipMemsetAsync(cursor, 0, N_NODES * 4, stream);
    edge_scatter<<<(E_TOT + 255) / 256, 256, 0, stream>>>(ei, row_start, cursor, ssrc);

    // ---- splits (blocked outputs) ----
    split_x<<<(N_NODES * 64 + 255) / 256, 256, 0, stream>>>(x, xh, xl, N_NODES * 64);
    split_lstm_w<<<(LAYERS * 1024 * 512 / 4 + 255) / 256, 256, 0, stream>>>(lstm_wih, lstm_whh, wlh, wll);
    split_gat_w<<<(LAYERS * 256 * 64 + 255) / 256, 256, 0, stream>>>(gat_w, gwh, gwl);
    split_wT<<<(256 * 256 + 255) / 256, 256, 0, stream>>>(lin1_w, l1h, l1l, 256, 256);
    split_wT<<<(64 * 256 + 255) / 256, 256, 0, stream>>>(lin2_w, l2h, l2l, 256, 64);

    // ---- init c + h ----
    hipMemsetAsync(c, 0, (size_t)N_NODES * HID * 4, stream);
    hipMemsetAsync(hbh[1], 0, (size_t)N_PAD * HID * 2, stream);   // not strictly needed
    hipMemsetAsync(hbl[1], 0, (size_t)N_PAD * HID * 2, stream);

    // ---- lin1: x0 = x @ lin1_w + b  (MFMA, blocked bf16-pair out) ----
    {
        dim3 grid((N_NODES + 127) / 128, 256 / 128);
        gemm_bf3<<<grid, 256, 0, stream>>>(xh, xl, xh, xl,
                                           l1h, l1l, lin1_b,
                                           nullptr, x0h, x0l, nullptr, nullptr,
                                           N_NODES, 256, 256, 2);
    }

    // ---- batched GAT: projection (fp16 row-major out), asd, aggregate ----
    {
        dim3 grid((N_NODES + 127) / 128, (LAYERS * DIM) / 128);
        gemm_bf3<<<grid, 256, 0, stream>>>(x0h, x0l, x0h, x0l,
                                           gwh, gwl, nullptr,
                                           nullptr, nullptr, nullptr, xwh, nullptr,
                                           N_NODES, LAYERS * DIM, 256, 1);
        int waves = LAYERS * N_NODES;
        compute_asd<<<(waves * 64 + 255) / 256, 256, 0, stream>>>(xwh, gat_asrc, gat_adst,
                                                                  a_s, a_d);
        gat_aggregate<<<(waves + 3) / 4, 256, 0, stream>>>(xwh, a_s, a_d, row_start, ssrc,
                                                           gat_b, htmph, htmpl);
    }

    // ---- LSTM chain (K=512 folded weights, fused cell epilogue) ----
    for (int l = 0; l < LAYERS; ++l) {
        const ushort* xch = (l == 0) ? x0h : hbh[(l - 1) & 1];
        const ushort* xcl = (l == 0) ? x0l : hbl[(l - 1) & 1];
        dim3 gridL((N_NODES + 127) / 128, 1024 / 128);
        gemm_bf3<<<gridL, 256, 0, stream>>>(
            htmph + (size_t)l * N_PAD * DIM, htmpl + (size_t)l * N_PAD * DIM,
            xch, xcl,
            wlh + (size_t)l * 1024 * 512, wll + (size_t)l * 1024 * 512,
            nullptr, nullptr, hbh[l & 1], hbl[l & 1], nullptr, c,
            N_NODES, 1024, 512, 3);
    }

    // ---- lin2: out = h @ lin2_w + b  (MFMA, fp32 out) ----
    {
        dim3 grid((N_NODES + 127) / 128, 1);
        gemm_bf3<<<grid, 256, 0, stream>>>(hbh[1], hbl[1], hbh[1], hbl[1],
                                           l2h, l2l, lin2_b,
                                           out, nullptr, nullptr, nullptr, nullptr,
                                           N_NODES, OUTD, 256, 0);
    }
}